// Round 1
// baseline (2204.739 us; speedup 1.0000x reference)
//
#include <hip/hip_runtime.h>

#define N_USERS   100000
#define N_ITEMS   50000
#define N_NODES   150000
#define EMBED_DIM 128
#define N_EDGES   6400000
#define USER_FLOATS (N_USERS * EMBED_DIM)   // 12,800,000
#define TOTAL_FLOATS (N_NODES * EMBED_DIM)  // 19,200,000
#define NB_SCAN   586                        // ceil(150000/256)

// ---------------- CSR build ----------------

__global__ __launch_bounds__(256) void hist_kernel(const int* __restrict__ edge_dst,
                                                   int* __restrict__ counts) {
    int e = blockIdx.x * 256 + threadIdx.x;
    if (e < N_EDGES) atomicAdd(&counts[edge_dst[e]], 1);
}

// Block-local exclusive scan of counts -> row_ptr (local part), block sums -> bsum
__global__ __launch_bounds__(256) void scan1_kernel(const int* __restrict__ counts,
                                                    int* __restrict__ row_ptr,
                                                    int* __restrict__ bsum) {
    __shared__ int tmp[256];
    int i = blockIdx.x * 256 + threadIdx.x;
    int v = (i < N_NODES) ? counts[i] : 0;
    tmp[threadIdx.x] = v;
    __syncthreads();
    for (int off = 1; off < 256; off <<= 1) {
        int t = (threadIdx.x >= off) ? tmp[threadIdx.x - off] : 0;
        __syncthreads();
        tmp[threadIdx.x] += t;
        __syncthreads();
    }
    int incl = tmp[threadIdx.x];
    if (i < N_NODES) row_ptr[i] = incl - v;       // exclusive local
    if (threadIdx.x == 255) bsum[blockIdx.x] = incl;
}

__global__ __launch_bounds__(1024) void scan2_kernel(int* __restrict__ bsum) {
    __shared__ int tmp[1024];
    int t = threadIdx.x;
    int v = (t < NB_SCAN) ? bsum[t] : 0;
    tmp[t] = v;
    __syncthreads();
    for (int off = 1; off < 1024; off <<= 1) {
        int x = (t >= off) ? tmp[t - off] : 0;
        __syncthreads();
        tmp[t] += x;
        __syncthreads();
    }
    if (t < NB_SCAN) bsum[t] = tmp[t] - v;        // exclusive
}

__global__ __launch_bounds__(256) void scan3_kernel(int* __restrict__ row_ptr,
                                                    const int* __restrict__ bsum) {
    int i = blockIdx.x * 256 + threadIdx.x;
    if (i < N_NODES) row_ptr[i] += bsum[blockIdx.x];
    if (i == 0) row_ptr[N_NODES] = N_EDGES;
}

__global__ __launch_bounds__(256) void scatter_kernel(const int* __restrict__ edge_src,
                                                      const int* __restrict__ edge_dst,
                                                      const float* __restrict__ edge_vals,
                                                      const int* __restrict__ row_ptr,
                                                      int* __restrict__ cursor,
                                                      int* __restrict__ col,
                                                      float* __restrict__ w) {
    int e = blockIdx.x * 256 + threadIdx.x;
    if (e >= N_EDGES) return;
    int dst = edge_dst[e];
    int slot = row_ptr[dst] + atomicAdd(&cursor[dst], 1);
    col[slot] = edge_src[e];
    w[slot] = edge_vals[e];
}

// ---------------- embedding init: cur = all_emb, acc = 0.25*all_emb ----------------

__global__ __launch_bounds__(256) void init_kernel(const float4* __restrict__ user_w,
                                                   const float4* __restrict__ item_w,
                                                   float4* __restrict__ cur,
                                                   float4* __restrict__ acc) {
    int i = blockIdx.x * 256 + threadIdx.x;              // float4 index
    if (i >= TOTAL_FLOATS / 4) return;
    float4 v;
    if (i < USER_FLOATS / 4) v = user_w[i];
    else                     v = item_w[i - USER_FLOATS / 4];
    cur[i] = v;
    float4 a;
    a.x = 0.25f * v.x; a.y = 0.25f * v.y; a.z = 0.25f * v.z; a.w = 0.25f * v.w;
    acc[i] = a;
}

// ---------------- SpMM: next = A*cur ; acc += 0.25*next ----------------
// one wave (64 lanes) per node, each lane owns 2 consecutive floats (float2)

__global__ __launch_bounds__(256) void spmm_kernel(const int* __restrict__ row_ptr,
                                                   const int* __restrict__ col,
                                                   const float* __restrict__ w,
                                                   const float2* __restrict__ cur,
                                                   float2* __restrict__ next,
                                                   float2* __restrict__ acc) {
    int wid = (blockIdx.x * 256 + threadIdx.x) >> 6;     // node id
    int lane = threadIdx.x & 63;
    if (wid >= N_NODES) return;
    int start = row_ptr[wid];
    int end   = row_ptr[wid + 1];
    float2 s; s.x = 0.f; s.y = 0.f;
    for (int base = start; base < end; base += 64) {
        int n = end - base;
        if (n > 64) n = 64;
        int idx = base + (lane < n ? lane : 0);
        int csrc = col[idx];
        float cw  = w[idx];
        if (n == 64) {
            #pragma unroll 8
            for (int j = 0; j < 64; ++j) {
                int   src = __shfl(csrc, j);
                float vw  = __shfl(cw, j);
                float2 v = cur[src * 64 + lane];
                s.x += vw * v.x;
                s.y += vw * v.y;
            }
        } else {
            for (int j = 0; j < n; ++j) {
                int   src = __shfl(csrc, j);
                float vw  = __shfl(cw, j);
                float2 v = cur[src * 64 + lane];
                s.x += vw * v.x;
                s.y += vw * v.y;
            }
        }
    }
    int o = wid * 64 + lane;
    next[o] = s;
    float2 a = acc[o];
    a.x += 0.25f * s.x;
    a.y += 0.25f * s.y;
    acc[o] = a;
}

// ---------------- launch ----------------

extern "C" void kernel_launch(void* const* d_in, const int* in_sizes, int n_in,
                              void* d_out, int out_size, void* d_ws, size_t ws_size,
                              hipStream_t stream) {
    const int*   edge_src  = (const int*)  d_in[0];
    const int*   edge_dst  = (const int*)  d_in[1];
    const float* edge_vals = (const float*)d_in[2];
    const float* user_w    = (const float*)d_in[3];
    const float* item_w    = (const float*)d_in[4];
    float* out = (float*)d_out;

    // workspace layout (bytes)
    char* ws = (char*)d_ws;
    float* cur     = (float*)(ws);                         // 76,800,000 B
    float* nxt     = (float*)(ws + 76800000);              // 76,800,000 B
    int*   row_ptr = (int*)  (ws + 153600000);             // 600,064 B (150001 ints)
    int*   bsum    = (int*)  (ws + 154200064);             // 4096 B
    int*   cursor  = (int*)  (ws + 154204160);             // 600,000 B (also counts)
    int*   col     = (int*)  (ws + 154804160);             // 25,600,000 B
    float* w       = (float*)(ws + 180404160);             // 25,600,000 B
    // total: 206,004,160 B

    const int EB = (N_EDGES + 255) / 256;       // 25000
    const int IB = (TOTAL_FLOATS / 4 + 255) / 256;
    const int SB = (N_NODES * 64 + 255) / 256;  // 37500

    // --- CSR build ---
    hipMemsetAsync(cursor, 0, N_NODES * sizeof(int), stream);   // counts
    hist_kernel<<<EB, 256, 0, stream>>>(edge_dst, cursor);
    scan1_kernel<<<NB_SCAN, 256, 0, stream>>>(cursor, row_ptr, bsum);
    scan2_kernel<<<1, 1024, 0, stream>>>(bsum);
    scan3_kernel<<<NB_SCAN, 256, 0, stream>>>(row_ptr, bsum);
    hipMemsetAsync(cursor, 0, N_NODES * sizeof(int), stream);
    scatter_kernel<<<EB, 256, 0, stream>>>(edge_src, edge_dst, edge_vals,
                                           row_ptr, cursor, col, w);

    // --- init ---
    init_kernel<<<IB, 256, 0, stream>>>((const float4*)user_w, (const float4*)item_w,
                                        (float4*)cur, (float4*)out);

    // --- 3 propagation layers ---
    float* a = cur;
    float* b = nxt;
    for (int layer = 0; layer < 3; ++layer) {
        spmm_kernel<<<SB, 256, 0, stream>>>(row_ptr, col, w,
                                            (const float2*)a, (float2*)b, (float2*)out);
        float* t = a; a = b; b = t;
    }
}

// Round 2
// 2044.397 us; speedup vs baseline: 1.0784x; 1.0784x over previous
//
#include <hip/hip_runtime.h>

#define N_USERS   100000
#define N_ITEMS   50000
#define N_NODES   150000
#define EMBED_DIM 128
#define N_EDGES   6400000
#define USER_FLOATS (N_USERS * EMBED_DIM)   // 12,800,000
#define TOTAL_FLOATS (N_NODES * EMBED_DIM)  // 19,200,000
#define NB_SCAN   586                        // ceil(150000/256)

// ---------------- CSR build ----------------

__global__ __launch_bounds__(256) void hist_kernel(const int* __restrict__ edge_dst,
                                                   int* __restrict__ counts) {
    int e = blockIdx.x * 256 + threadIdx.x;
    if (e < N_EDGES) atomicAdd(&counts[edge_dst[e]], 1);
}

// Block-local exclusive scan of counts -> row_ptr (local part), block sums -> bsum
__global__ __launch_bounds__(256) void scan1_kernel(const int* __restrict__ counts,
                                                    int* __restrict__ row_ptr,
                                                    int* __restrict__ bsum) {
    __shared__ int tmp[256];
    int i = blockIdx.x * 256 + threadIdx.x;
    int v = (i < N_NODES) ? counts[i] : 0;
    tmp[threadIdx.x] = v;
    __syncthreads();
    for (int off = 1; off < 256; off <<= 1) {
        int t = (threadIdx.x >= off) ? tmp[threadIdx.x - off] : 0;
        __syncthreads();
        tmp[threadIdx.x] += t;
        __syncthreads();
    }
    int incl = tmp[threadIdx.x];
    if (i < N_NODES) row_ptr[i] = incl - v;       // exclusive local
    if (threadIdx.x == 255) bsum[blockIdx.x] = incl;
}

__global__ __launch_bounds__(1024) void scan2_kernel(int* __restrict__ bsum) {
    __shared__ int tmp[1024];
    int t = threadIdx.x;
    int v = (t < NB_SCAN) ? bsum[t] : 0;
    tmp[t] = v;
    __syncthreads();
    for (int off = 1; off < 1024; off <<= 1) {
        int x = (t >= off) ? tmp[t - off] : 0;
        __syncthreads();
        tmp[t] += x;
        __syncthreads();
    }
    if (t < NB_SCAN) bsum[t] = tmp[t] - v;        // exclusive
}

__global__ __launch_bounds__(256) void scan3_kernel(int* __restrict__ row_ptr,
                                                    const int* __restrict__ bsum) {
    int i = blockIdx.x * 256 + threadIdx.x;
    if (i < N_NODES) row_ptr[i] += bsum[blockIdx.x];
    if (i == 0) row_ptr[N_NODES] = N_EDGES;
}

// Pack (src, weight) into one int2 -> single 8B random write per edge
__global__ __launch_bounds__(256) void scatter_kernel(const int* __restrict__ edge_src,
                                                      const int* __restrict__ edge_dst,
                                                      const float* __restrict__ edge_vals,
                                                      const int* __restrict__ row_ptr,
                                                      int* __restrict__ cursor,
                                                      int2* __restrict__ cw) {
    int e = blockIdx.x * 256 + threadIdx.x;
    if (e >= N_EDGES) return;
    int dst = edge_dst[e];
    int slot = row_ptr[dst] + atomicAdd(&cursor[dst], 1);
    int2 p;
    p.x = edge_src[e];
    p.y = __float_as_int(edge_vals[e]);
    cw[slot] = p;
}

// ---------------- embedding init: cur = all_emb, acc(out) = 0.25*all_emb ----------------

__global__ __launch_bounds__(256) void init_kernel(const float4* __restrict__ user_w,
                                                   const float4* __restrict__ item_w,
                                                   float4* __restrict__ cur,
                                                   float4* __restrict__ acc) {
    int i = blockIdx.x * 256 + threadIdx.x;              // float4 index
    if (i >= TOTAL_FLOATS / 4) return;
    float4 v;
    if (i < USER_FLOATS / 4) v = user_w[i];
    else                     v = item_w[i - USER_FLOATS / 4];
    cur[i] = v;
    float4 a;
    a.x = 0.25f * v.x; a.y = 0.25f * v.y; a.z = 0.25f * v.z; a.w = 0.25f * v.w;
    acc[i] = a;
}

// ---------------- SpMM: next = A*cur ; acc += 0.25*next ----------------
// One wave (64 lanes) per node. Half-wave (32 lanes) covers the 128-dim row
// as 32 x float4; the two halves process two different source rows per
// iteration, combined by shfl_xor(32) at the end.

__global__ __launch_bounds__(256) void spmm_kernel(const int* __restrict__ row_ptr,
                                                   const int2* __restrict__ cw,
                                                   const float4* __restrict__ cur,
                                                   float4* __restrict__ next,
                                                   float4* __restrict__ acc) {
    int wid  = (blockIdx.x * 256 + threadIdx.x) >> 6;    // node id
    int lane = threadIdx.x & 63;
    int half = lane >> 5;                                // 0 or 1
    int l    = lane & 31;                                // float4 index in row
    if (wid >= N_NODES) return;
    int start = row_ptr[wid];
    int end   = row_ptr[wid + 1];
    float4 s; s.x = 0.f; s.y = 0.f; s.z = 0.f; s.w = 0.f;
    for (int base = start; base < end; base += 64) {
        int n = end - base;
        if (n > 64) n = 64;
        int idx = base + (lane < n ? lane : n - 1);
        int2 p = cw[idx];
        int   csrc = p.x;
        float cwf  = (lane < n) ? __int_as_float(p.y) : 0.f;
        int m = (n + 1) >> 1;                            // source pairs
        for (int j = 0; j < m; ++j) {
            int k = 2 * j + half;                        // this half's source
            int   src = __shfl(csrc, k);
            float vw  = __shfl(cwf, k);                  // 0 for padded tail
            float4 v = cur[src * 32 + l];
            s.x += vw * v.x;
            s.y += vw * v.y;
            s.z += vw * v.z;
            s.w += vw * v.w;
        }
    }
    // combine the two half-wave partials
    s.x += __shfl_xor(s.x, 32);
    s.y += __shfl_xor(s.y, 32);
    s.z += __shfl_xor(s.z, 32);
    s.w += __shfl_xor(s.w, 32);
    int o = wid * 32 + l;
    if (half == 0) {
        next[o] = s;
    } else {
        float4 a = acc[o];
        a.x += 0.25f * s.x;
        a.y += 0.25f * s.y;
        a.z += 0.25f * s.z;
        a.w += 0.25f * s.w;
        acc[o] = a;
    }
}

// ---------------- launch ----------------

extern "C" void kernel_launch(void* const* d_in, const int* in_sizes, int n_in,
                              void* d_out, int out_size, void* d_ws, size_t ws_size,
                              hipStream_t stream) {
    const int*   edge_src  = (const int*)  d_in[0];
    const int*   edge_dst  = (const int*)  d_in[1];
    const float* edge_vals = (const float*)d_in[2];
    const float* user_w    = (const float*)d_in[3];
    const float* item_w    = (const float*)d_in[4];
    float* out = (float*)d_out;

    // workspace layout (bytes)
    char* ws = (char*)d_ws;
    float* cur     = (float*)(ws);                         // 76,800,000 B
    float* nxt     = (float*)(ws + 76800000);              // 76,800,000 B
    int*   row_ptr = (int*)  (ws + 153600000);             // 600,064 B (150001 ints)
    int*   bsum    = (int*)  (ws + 154200064);             // 4096 B
    int*   cursor  = (int*)  (ws + 154204160);             // 600,000 B (also counts)
    int2*  cw      = (int2*) (ws + 154804160);             // 51,200,000 B
    // total: 206,004,160 B

    const int EB = (N_EDGES + 255) / 256;       // 25000
    const int IB = (TOTAL_FLOATS / 4 + 255) / 256;
    const int SB = (N_NODES * 64 + 255) / 256;  // 37500

    // --- CSR build ---
    hipMemsetAsync(cursor, 0, N_NODES * sizeof(int), stream);   // counts
    hist_kernel<<<EB, 256, 0, stream>>>(edge_dst, cursor);
    scan1_kernel<<<NB_SCAN, 256, 0, stream>>>(cursor, row_ptr, bsum);
    scan2_kernel<<<1, 1024, 0, stream>>>(bsum);
    scan3_kernel<<<NB_SCAN, 256, 0, stream>>>(row_ptr, bsum);
    hipMemsetAsync(cursor, 0, N_NODES * sizeof(int), stream);
    scatter_kernel<<<EB, 256, 0, stream>>>(edge_src, edge_dst, edge_vals,
                                           row_ptr, cursor, cw);

    // --- init ---
    init_kernel<<<IB, 256, 0, stream>>>((const float4*)user_w, (const float4*)item_w,
                                        (float4*)cur, (float4*)out);

    // --- 3 propagation layers ---
    float* a = cur;
    float* b = nxt;
    for (int layer = 0; layer < 3; ++layer) {
        spmm_kernel<<<SB, 256, 0, stream>>>(row_ptr, cw,
                                            (const float4*)a, (float4*)b, (float4*)out);
        float* t = a; a = b; b = t;
    }
}

// Round 3
// 1367.340 us; speedup vs baseline: 1.6124x; 1.4952x over previous
//
#include <hip/hip_runtime.h>

#define N_USERS   100000
#define N_ITEMS   50000
#define N_NODES   150000
#define EMBED_DIM 128
#define N_EDGES   6400000
#define USER_FLOATS (N_USERS * EMBED_DIM)   // 12,800,000
#define TOTAL_FLOATS (N_NODES * EMBED_DIM)  // 19,200,000
#define NB_SCAN   586                        // ceil(150000/256)

// fp32 -> bf16 round-to-nearest-even (returns low 16 bits)
static __device__ __forceinline__ unsigned bf16_rne(float f) {
    unsigned u = __float_as_uint(f);
    return (u + 0x7fffu + ((u >> 16) & 1u)) >> 16;
}

// ---------------- CSR build ----------------

__global__ __launch_bounds__(256) void hist_kernel(const int* __restrict__ edge_dst,
                                                   int* __restrict__ counts) {
    int e = blockIdx.x * 256 + threadIdx.x;
    if (e < N_EDGES) atomicAdd(&counts[edge_dst[e]], 1);
}

__global__ __launch_bounds__(256) void scan1_kernel(const int* __restrict__ counts,
                                                    int* __restrict__ row_ptr,
                                                    int* __restrict__ bsum) {
    __shared__ int tmp[256];
    int i = blockIdx.x * 256 + threadIdx.x;
    int v = (i < N_NODES) ? counts[i] : 0;
    tmp[threadIdx.x] = v;
    __syncthreads();
    for (int off = 1; off < 256; off <<= 1) {
        int t = (threadIdx.x >= off) ? tmp[threadIdx.x - off] : 0;
        __syncthreads();
        tmp[threadIdx.x] += t;
        __syncthreads();
    }
    int incl = tmp[threadIdx.x];
    if (i < N_NODES) row_ptr[i] = incl - v;       // exclusive local
    if (threadIdx.x == 255) bsum[blockIdx.x] = incl;
}

__global__ __launch_bounds__(1024) void scan2_kernel(int* __restrict__ bsum) {
    __shared__ int tmp[1024];
    int t = threadIdx.x;
    int v = (t < NB_SCAN) ? bsum[t] : 0;
    tmp[t] = v;
    __syncthreads();
    for (int off = 1; off < 1024; off <<= 1) {
        int x = (t >= off) ? tmp[t - off] : 0;
        __syncthreads();
        tmp[t] += x;
        __syncthreads();
    }
    if (t < NB_SCAN) bsum[t] = tmp[t] - v;        // exclusive
}

__global__ __launch_bounds__(256) void scan3_kernel(int* __restrict__ row_ptr,
                                                    const int* __restrict__ bsum) {
    int i = blockIdx.x * 256 + threadIdx.x;
    if (i < N_NODES) row_ptr[i] += bsum[blockIdx.x];
    if (i == 0) row_ptr[N_NODES] = N_EDGES;
}

// Pack (src, weight) into one int2 -> single 8B random write per edge
__global__ __launch_bounds__(256) void scatter_kernel(const int* __restrict__ edge_src,
                                                      const int* __restrict__ edge_dst,
                                                      const float* __restrict__ edge_vals,
                                                      const int* __restrict__ row_ptr,
                                                      int* __restrict__ cursor,
                                                      int2* __restrict__ cw) {
    int e = blockIdx.x * 256 + threadIdx.x;
    if (e >= N_EDGES) return;
    int dst = edge_dst[e];
    int slot = row_ptr[dst] + atomicAdd(&cursor[dst], 1);
    int2 p;
    p.x = edge_src[e];
    p.y = __float_as_int(edge_vals[e]);
    cw[slot] = p;
}

// ---------------- init: cur(bf16) = all_emb, acc(out, fp32) = 0.25*all_emb ----------------

__global__ __launch_bounds__(256) void init_kernel(const float4* __restrict__ user_w,
                                                   const float4* __restrict__ item_w,
                                                   uint2* __restrict__ cur,
                                                   float4* __restrict__ acc) {
    int i = blockIdx.x * 256 + threadIdx.x;              // float4 index
    if (i >= TOTAL_FLOATS / 4) return;
    float4 v;
    if (i < USER_FLOATS / 4) v = user_w[i];
    else                     v = item_w[i - USER_FLOATS / 4];
    uint2 c;
    c.x = bf16_rne(v.x) | (bf16_rne(v.y) << 16);
    c.y = bf16_rne(v.z) | (bf16_rne(v.w) << 16);
    cur[i] = c;
    float4 a;
    a.x = 0.25f * v.x; a.y = 0.25f * v.y; a.z = 0.25f * v.z; a.w = 0.25f * v.w;
    acc[i] = a;
}

// ---------------- SpMM: next(bf16) = A*cur(bf16) ; acc(fp32) += 0.25*next ----------------
// One wave per node. Quarter-wave (16 lanes x 16B = 8 bf16 dims/lane) covers the
// 128-dim row; the 4 quarters process 4 different source rows per iteration,
// combined by shfl_xor(16)+shfl_xor(32).

__global__ __launch_bounds__(256) void spmm_kernel(const int* __restrict__ row_ptr,
                                                   const int2* __restrict__ cw,
                                                   const uint4* __restrict__ cur,
                                                   uint4* __restrict__ next,
                                                   float4* __restrict__ acc,
                                                   int write_next) {
    int wid  = (blockIdx.x * 256 + threadIdx.x) >> 6;    // node id
    int lane = threadIdx.x & 63;
    int q    = lane >> 4;                                // quarter 0..3
    int l    = lane & 15;                                // uint4 index in row
    if (wid >= N_NODES) return;
    int start = row_ptr[wid];
    int end   = row_ptr[wid + 1];
    float s[8];
    #pragma unroll
    for (int c = 0; c < 8; ++c) s[c] = 0.f;
    for (int base = start; base < end; base += 64) {
        int n = end - base;
        if (n > 64) n = 64;
        int idx = base + (lane < n ? lane : n - 1);
        int2 p = cw[idx];
        float cwf = (lane < n) ? __int_as_float(p.y) : 0.f;
        int m = (n + 3) >> 2;
        for (int j = 0; j < m; ++j) {
            int k = 4 * j + q;                           // this quarter's source
            int   src = __shfl(p.x, k);
            float vw  = __shfl(cwf, k);                  // 0 for padded tail
            uint4 v = cur[src * 16 + l];
            s[0] += vw * __uint_as_float(v.x << 16);
            s[1] += vw * __uint_as_float(v.x & 0xffff0000u);
            s[2] += vw * __uint_as_float(v.y << 16);
            s[3] += vw * __uint_as_float(v.y & 0xffff0000u);
            s[4] += vw * __uint_as_float(v.z << 16);
            s[5] += vw * __uint_as_float(v.z & 0xffff0000u);
            s[6] += vw * __uint_as_float(v.w << 16);
            s[7] += vw * __uint_as_float(v.w & 0xffff0000u);
        }
    }
    #pragma unroll
    for (int c = 0; c < 8; ++c) {
        s[c] += __shfl_xor(s[c], 16);
        s[c] += __shfl_xor(s[c], 32);
    }
    if (q == 0) {
        if (write_next) {
            uint4 o;
            o.x = bf16_rne(s[0]) | (bf16_rne(s[1]) << 16);
            o.y = bf16_rne(s[2]) | (bf16_rne(s[3]) << 16);
            o.z = bf16_rne(s[4]) | (bf16_rne(s[5]) << 16);
            o.w = bf16_rne(s[6]) | (bf16_rne(s[7]) << 16);
            next[wid * 16 + l] = o;
        }
    } else if (q == 1) {
        int o = wid * 32 + 2 * l;
        float4 a = acc[o];
        a.x += 0.25f * s[0]; a.y += 0.25f * s[1];
        a.z += 0.25f * s[2]; a.w += 0.25f * s[3];
        acc[o] = a;
        float4 b = acc[o + 1];
        b.x += 0.25f * s[4]; b.y += 0.25f * s[5];
        b.z += 0.25f * s[6]; b.w += 0.25f * s[7];
        acc[o + 1] = b;
    }
}

// ---------------- launch ----------------

extern "C" void kernel_launch(void* const* d_in, const int* in_sizes, int n_in,
                              void* d_out, int out_size, void* d_ws, size_t ws_size,
                              hipStream_t stream) {
    const int*   edge_src  = (const int*)  d_in[0];
    const int*   edge_dst  = (const int*)  d_in[1];
    const float* edge_vals = (const float*)d_in[2];
    const float* user_w    = (const float*)d_in[3];
    const float* item_w    = (const float*)d_in[4];
    float* out = (float*)d_out;

    // workspace layout (bytes)
    char* ws = (char*)d_ws;
    unsigned* cur = (unsigned*)(ws);                     // bf16: 38,400,000 B
    unsigned* nxt = (unsigned*)(ws + 38400000);          // bf16: 38,400,000 B
    int* row_ptr  = (int*)    (ws + 76800000);           // 600,064 B (150001 ints)
    int* bsum     = (int*)    (ws + 77400064);           // 4,096 B
    int* cursor   = (int*)    (ws + 77404160);           // 600,000 B (also counts)
    int2* cw      = (int2*)   (ws + 78004160);           // 51,200,000 B
    // total: 129,204,160 B

    const int EB = (N_EDGES + 255) / 256;       // 25000
    const int IB = (TOTAL_FLOATS / 4 + 255) / 256;
    const int SB = (N_NODES * 64 + 255) / 256;  // 37500

    // --- CSR build ---
    hipMemsetAsync(cursor, 0, N_NODES * sizeof(int), stream);   // counts
    hist_kernel<<<EB, 256, 0, stream>>>(edge_dst, cursor);
    scan1_kernel<<<NB_SCAN, 256, 0, stream>>>(cursor, row_ptr, bsum);
    scan2_kernel<<<1, 1024, 0, stream>>>(bsum);
    scan3_kernel<<<NB_SCAN, 256, 0, stream>>>(row_ptr, bsum);
    hipMemsetAsync(cursor, 0, N_NODES * sizeof(int), stream);
    scatter_kernel<<<EB, 256, 0, stream>>>(edge_src, edge_dst, edge_vals,
                                           row_ptr, cursor, cw);

    // --- init ---
    init_kernel<<<IB, 256, 0, stream>>>((const float4*)user_w, (const float4*)item_w,
                                        (uint2*)cur, (float4*)out);

    // --- 3 propagation layers ---
    unsigned* a = cur;
    unsigned* b = nxt;
    for (int layer = 0; layer < 3; ++layer) {
        spmm_kernel<<<SB, 256, 0, stream>>>(row_ptr, cw,
                                            (const uint4*)a, (uint4*)b, (float4*)out,
                                            layer < 2 ? 1 : 0);
        unsigned* t = a; a = b; b = t;
    }
}